// Round 10
// baseline (193.324 us; speedup 1.0000x reference)
//
#include <hip/hip_runtime.h>
#include <math.h>

// ---- variant toggles (validated in R6) ----
#define BLAS_FMA 1
#define SYR2_VARIANT 0

#define DEV static __device__ __forceinline__

// f32 IEEE ops, opaque to fp-contract
DEV float fA(float a, float b){ return __fadd_rn(a,b); }
DEV float fSb(float a, float b){ return __fsub_rn(a,b); }
DEV float fM(float a, float b){ return __fmul_rn(a,b); }
DEV float fDv(float a, float b){ return __fdiv_rn(a,b); }
DEV float fQ(float a){ return __fsqrt_rn(a); }
DEV float fF(float a, float b, float c){ return __builtin_fmaf(a,b,c); }
DEV float fSGN(float a, float b){ return copysignf(a,b); }

DEV float slapy2f(float x, float y){
  float xa=fabsf(x), ya=fabsf(y);
  float w=fmaxf(xa,ya), z=fminf(xa,ya);
  if (z==0.0f) return w;
  float t=fDv(z,w);
  return fM(w, fQ(fA(1.0f, fM(t,t))));
}

// LAPACK >=3.10 slartg (f32)
DEV void slartgf(float f, float g, float* c, float* s, float* r){
  const float safmin=1.17549435e-38f;
  const float safmax=8.50705917e+37f;
  const float rtmin=1.08420217e-19f;
  const float rtmax=6.52169543e+18f;
  float f1=fabsf(f), g1=fabsf(g);
  if (g==0.0f){ *c=1.0f; *s=0.0f; *r=f; }
  else if (f==0.0f){ *c=0.0f; *s=fSGN(1.0f,g); *r=g1; }
  else {
    if (f1>rtmin && f1<rtmax && g1>rtmin && g1<rtmax){
      float d=fQ(fA(fM(f,f), fM(g,g)));
      *c=fDv(f1,d);
      *r=fSGN(d,f);
      *s=fDv(g,*r);
    } else {
      float u=fminf(safmax, fmaxf(safmin, fmaxf(f1,g1)));
      float fs=fDv(f,u), gs=fDv(g,u);
      float d=fQ(fA(fM(fs,fs), fM(gs,gs)));
      *c=fDv(fabsf(fs), d);
      *r=fSGN(d,f);
      *s=fDv(gs,*r);
      *r=fM(*r,u);
    }
  }
}

DEV void slaev2f(float a, float b, float c, float* rt1, float* rt2, float* cs1, float* sn1){
  float sm=fA(a,c);
  float df=fSb(a,c);
  float adf=fabsf(df);
  float tb=fA(b,b);
  float ab=fabsf(tb);
  float acmx, acmn;
  if (fabsf(a)>fabsf(c)){ acmx=a; acmn=c; } else { acmx=c; acmn=a; }
  float rt;
  if (adf>ab){ float t=fDv(ab,adf); rt=fM(adf, fQ(fA(1.0f, fM(t,t)))); }
  else if (adf<ab){ float t=fDv(adf,ab); rt=fM(ab, fQ(fA(1.0f, fM(t,t)))); }
  else { rt=fM(ab, fQ(2.0f)); }
  int sgn1;
  if (sm<0.0f){
    *rt1=fM(0.5f, fSb(sm,rt)); sgn1=-1;
    *rt2=fSb(fM(fDv(acmx,*rt1),acmn), fM(fDv(b,*rt1),b));
  } else if (sm>0.0f){
    *rt1=fM(0.5f, fA(sm,rt)); sgn1=1;
    *rt2=fSb(fM(fDv(acmx,*rt1),acmn), fM(fDv(b,*rt1),b));
  } else {
    *rt1=fM(0.5f,rt); *rt2=fM(-0.5f,rt); sgn1=1;
  }
  float cs; int sgn2;
  if (df>=0.0f){ cs=fA(df,rt); sgn2=1; } else { cs=fSb(df,rt); sgn2=-1; }
  float acs=fabsf(cs);
  if (acs>ab){
    float ct=fDv(-tb,cs);
    *sn1=fDv(1.0f, fQ(fA(1.0f, fM(ct,ct))));
    *cs1=fM(ct,*sn1);
  } else {
    if (ab==0.0f){ *cs1=1.0f; *sn1=0.0f; }
    else {
      float tn=fDv(-cs,tb);
      *cs1=fDv(1.0f, fQ(fA(1.0f, fM(tn,tn))));
      *sn1=fM(tn,*cs1);
    }
  }
  if (sgn1==sgn2){ float tn=*cs1; *cs1=-(*sn1); *sn1=tn; }
}

// f32 ssyevd(n=3,'L','V') emulating scipy-openblas32.
// R14: n=3 control-flow specialization (R8-validated, absmax 0.0009765625).
DEV void eig3_smallest(float a00, float a10, float a20, float a11, float a21, float a22,
                       float* vout){
  const float RMIN=3.13916472e-16f;
  const float RMAX=3.18559313e+15f;
  float anrm=fmaxf(fabsf(a00), fmaxf(fabsf(a10), fmaxf(fabsf(a20),
             fmaxf(fabsf(a11), fmaxf(fabsf(a21), fabsf(a22))))));
  if (anrm>0.0f && anrm<RMIN){
    float sig=fDv(RMIN,anrm);
    a00=fM(a00,sig); a10=fM(a10,sig); a20=fM(a20,sig);
    a11=fM(a11,sig); a21=fM(a21,sig); a22=fM(a22,sig);
  } else if (anrm>RMAX){
    float sig=fDv(RMAX,anrm);
    a00=fM(a00,sig); a10=fM(a10,sig); a20=fM(a20,sig);
    a11=fM(a11,sig); a21=fM(a21,sig); a22=fM(a22,sig);
  }
  float d0,d1,d2, e0,e1;
  float tau1=0.0f, hv2=0.0f;
  {
    float xnorm=fabsf(a20);
    if (xnorm==0.0f){
      tau1=0.0f;
      d0=a00; d1=a11; d2=a22;
      e0=a10; e1=a21;
    } else {
      float alpha=a10;
      float beta=-fSGN(slapy2f(alpha,xnorm), alpha);
      tau1=fDv(fSb(beta,alpha), beta);
      float rs=fDv(1.0f, fSb(alpha,beta));
      hv2=fM(a20, rs);
      float t2a=fM(a21, hv2);
#if BLAS_FMA
      float w1=fF(tau1, t2a, fM(tau1, a11));
      float w2=fF(fM(tau1,hv2), a22, fM(tau1, a21));
      float sd=fF(hv2, w2, w1);
#else
      float w1=fA(fM(tau1,a11), fM(tau1,t2a));
      float w2=fA(fM(tau1,a21), fM(fM(tau1,hv2),a22));
      float sd=fA(w1, fM(w2,hv2));
#endif
      float al2=fM(fM(-0.5f,tau1), sd);
      float nw1=fA(w1, al2);
#if BLAS_FMA
      float nw2=fF(al2, hv2, w2);
#else
      float nw2=fA(w2, fM(al2,hv2));
#endif
      w1=nw1; w2=nw2;
      float b11, b21, b22;
#if SYR2_VARIANT==0
      b11=fA(a11, fM(-2.0f, w1));
      b21=fA(a21, fF(hv2, -w1, -w2));
      b22=fA(a22, fF(hv2, -w2, fM(w2, -hv2)));
#elif SYR2_VARIANT==1
      b11=fSb(fSb(a11, w1), w1);
      b21=fSb(fF(hv2, -w1, a21), w2);
      b22=fF(w2, -hv2, fF(hv2, -w2, a22));
#else
      b11=fA(fA(a11, -w1), -w1);
      b21=fA(fA(a21, fM(hv2,-w1)), -w2);
      b22=fA(fA(a22, fM(hv2,-w2)), fM(w2,-hv2));
#endif
      d0=a00; d1=b11; d2=b22;
      e0=beta; e1=b21;
    }
  }
  // z column-major: z[r + 3*c] ; col0={z0,z1,z2} col1={z3,z4,z5} col2={z6,z7,z8}
  float z0=1.0f,z1=0.0f,z2=0.0f, z3=0.0f,z4=1.0f,z5=0.0f, z6=0.0f,z7=0.0f,z8=1.0f;

#define DGET(iA)   ((iA)==0?d0:((iA)==1?d1:d2))
#define DSET(iA,vA) do{ float _dsv=(vA); int _dsi=(iA); \
  d0=(_dsi==0)?_dsv:d0; d1=(_dsi==1)?_dsv:d1; d2=(_dsi==2)?_dsv:d2; }while(0)
#define EGET(iA)   ((iA)==0?e0:e1)
#define ESET(iA,vA) do{ float _esv=(vA); int _esi=(iA); \
  e0=(_esi==0)?_esv:e0; e1=(_esi==1)?_esv:e1; }while(0)
#define ZGET(rA,cA) ((cA)==0? ((rA)==0?z0:((rA)==1?z1:z2)) : ((cA)==1? ((rA)==0?z3:((rA)==1?z4:z5)) : ((rA)==0?z6:((rA)==1?z7:z8))))
#define ZSET(rA,cA,vA) do{ float _zsv=(vA); int _zsr=(rA), _zsc=(cA); \
  z0=(_zsr==0&&_zsc==0)?_zsv:z0; z1=(_zsr==1&&_zsc==0)?_zsv:z1; z2=(_zsr==2&&_zsc==0)?_zsv:z2; \
  z3=(_zsr==0&&_zsc==1)?_zsv:z3; z4=(_zsr==1&&_zsc==1)?_zsv:z4; z5=(_zsr==2&&_zsc==1)?_zsv:z5; \
  z6=(_zsr==0&&_zsc==2)?_zsv:z6; z7=(_zsr==1&&_zsc==2)?_zsv:z7; z8=(_zsr==2&&_zsc==2)?_zsv:z8; }while(0)
// constant-column plane rotations
#define ZROT0(ccA,ssA) do{ float _zc=(ccA), _zs=(ssA); \
  float _t0=z3, _a0=z0; z3=fSb(fM(_zc,_t0),fM(_zs,_a0)); z0=fA(fM(_zs,_t0),fM(_zc,_a0)); \
  float _t1=z4, _a1=z1; z4=fSb(fM(_zc,_t1),fM(_zs,_a1)); z1=fA(fM(_zs,_t1),fM(_zc,_a1)); \
  float _t2=z5, _a2=z2; z5=fSb(fM(_zc,_t2),fM(_zs,_a2)); z2=fA(fM(_zs,_t2),fM(_zc,_a2)); }while(0)
#define ZROT1(ccA,ssA) do{ float _zc=(ccA), _zs=(ssA); \
  float _t0=z6, _a0=z3; z6=fSb(fM(_zc,_t0),fM(_zs,_a0)); z3=fA(fM(_zs,_t0),fM(_zc,_a0)); \
  float _t1=z7, _a1=z4; z7=fSb(fM(_zc,_t1),fM(_zs,_a1)); z4=fA(fM(_zs,_t1),fM(_zc,_a1)); \
  float _t2=z8, _a2=z5; z8=fSb(fM(_zc,_t2),fM(_zs,_a2)); z5=fA(fM(_zs,_t2),fM(_zc,_a2)); }while(0)
#define ZSWAPC(caA,cbA) do{ int _zwa=(caA), _zwb=(cbA); \
  _Pragma("unroll") \
  for (int _zwr=0;_zwr<3;++_zwr){ \
    float _zwta=ZGET(_zwr,_zwa); float _zwtb=ZGET(_zwr,_zwb); \
    ZSET(_zwr,_zwa,_zwtb); ZSET(_zwr,_zwb,_zwta); \
  } }while(0)

  const float EPS=5.96046448e-08f;
  const float EPS2=3.55271368e-15f;
  const float SAFMIN=1.17549435e-38f;
  const float SSFMAX=3.07445735e+18f;
  const float SSFMIN=3.05175781e-05f;
  int l1=1, jtot=0; const int nmaxit=90;
  bool skip_sort=false;
  while (l1<=3){
    if (l1>1) ESET(l1-2, 0.0f);
    int m=3;
    for (int mm=l1; mm<=2; ++mm){
      float tst=fabsf(EGET(mm-1));
      if (tst==0.0f){ m=mm; break; }
      if (tst<=fM(fM(fQ(fabsf(DGET(mm-1))), fQ(fabsf(DGET(mm)))), EPS)){ ESET(mm-1,0.0f); m=mm; break; }
    }
    int l=l1, lsv=l, lend=m, lendsv=m;
    l1=m+1;
    if (lend==l) continue;
    float anorm=fabsf(DGET(lend-1));
    for (int i=l; i<=lend-1; ++i){ anorm=fmaxf(anorm,fabsf(DGET(i-1))); anorm=fmaxf(anorm,fabsf(EGET(i-1))); }
    if (anorm==0.0f) continue;
    int iscale=0;
    if (anorm>SSFMAX){
      iscale=1; float mv=fDv(SSFMAX,anorm);
      for (int i=l;i<=lend;++i) DSET(i-1, fM(DGET(i-1),mv));
      for (int i=l;i<=lend-1;++i) ESET(i-1, fM(EGET(i-1),mv));
    } else if (anorm<SSFMIN){
      iscale=2; float mv=fDv(SSFMIN,anorm);
      for (int i=l;i<=lend;++i) DSET(i-1, fM(DGET(i-1),mv));
      for (int i=l;i<=lend-1;++i) ESET(i-1, fM(EGET(i-1),mv));
    }
    if (fabsf(DGET(lend-1))<fabsf(DGET(l-1))){ lend=lsv; l=lendsv; }
    if (lend>l){
      for (;;){
        int M=lend;
        if (l!=lend){
          for (int mm=l; mm<=lend-1; ++mm){
            float ee=fabsf(EGET(mm-1));
            float tst=fM(ee,ee);
            if (tst<=fA(fM(fM(EPS2,fabsf(DGET(mm-1))), fabsf(DGET(mm))), SAFMIN)){ M=mm; break; }
          }
        }
        if (M<lend) ESET(M-1,0.0f);
        float p=DGET(l-1);
        if (M==l){
          l+=1;
          if (l<=lend) continue; else break;
        }
        if (M==l+1){
          float rt1,rt2,cc,ss;
          if (l==1){
            slaev2f(d0, e0, d1, &rt1,&rt2,&cc,&ss);
            ZROT0(cc, ss);
            d0=rt1; d1=rt2; e0=0.0f;
          } else { // l==2
            slaev2f(d1, e1, d2, &rt1,&rt2,&cc,&ss);
            ZROT1(cc, ss);
            d1=rt1; d2=rt2; e1=0.0f;
          }
          l+=2;
          if (l<=lend) continue; else break;
        }
        if (jtot==nmaxit) break;
        ++jtot;
        float g=fDv(fSb(d1,p), fM(2.0f,e0));
        float r=slapy2f(g,1.0f);
        g=fA(fSb(d2,p), fDv(e0, fA(g, fSGN(r,g))));
        float s=1.0f, c=1.0f; p=0.0f;
        float cr0,cr1,sr0,sr1;
        { // i=2
          float f=fM(s,e1);
          float bb=fM(c,e1);
          slartgf(g,f,&c,&s,&r);
          g=fSb(d2,p);
          r=fA(fM(fSb(d1,g),s), fM(fM(2.0f,c),bb));
          p=fM(s,r);
          d2=fA(g,p);
          g=fSb(fM(c,r),bb);
          cr1=c; sr1=-s;
        }
        { // i=1
          float f=fM(s,e0);
          float bb=fM(c,e0);
          slartgf(g,f,&c,&s,&r);
          e1=r;
          g=fSb(d1,p);
          r=fA(fM(fSb(d0,g),s), fM(fM(2.0f,c),bb));
          p=fM(s,r);
          d1=fA(g,p);
          g=fSb(fM(c,r),bb);
          cr0=c; sr0=-s;
        }
        if (cr1!=1.0f || sr1!=0.0f) ZROT1(cr1, sr1);
        if (cr0!=1.0f || sr0!=0.0f) ZROT0(cr0, sr0);
        d0=fSb(d0,p);
        e0=g;
      }
    } else {
      for (;;){
        int M=lend;
        if (l!=lend){
          for (int mm=l; mm>=lend+1; --mm){
            float ee=fabsf(EGET(mm-2));
            float tst=fM(ee,ee);
            if (tst<=fA(fM(fM(EPS2,fabsf(DGET(mm-1))), fabsf(DGET(mm-2))), SAFMIN)){ M=mm; break; }
          }
        }
        if (M>lend) ESET(M-2,0.0f);
        float p=DGET(l-1);
        if (M==l){
          l-=1;
          if (l>=lend) continue; else break;
        }
        if (M==l-1){
          float rt1,rt2,cc,ss;
          if (l==3){
            slaev2f(d1, e1, d2, &rt1,&rt2,&cc,&ss);
            ZROT1(cc, ss);
            d1=rt1; d2=rt2; e1=0.0f;
          } else { // l==2
            slaev2f(d0, e0, d1, &rt1,&rt2,&cc,&ss);
            ZROT0(cc, ss);
            d0=rt1; d1=rt2; e0=0.0f;
          }
          l-=2;
          if (l>=lend) continue; else break;
        }
        if (jtot==nmaxit) break;
        ++jtot;
        float g=fDv(fSb(d1,p), fM(2.0f,e1));
        float r=slapy2f(g,1.0f);
        g=fA(fSb(d0,p), fDv(e1, fA(g, fSGN(r,g))));
        float s=1.0f, c=1.0f; p=0.0f;
        float cr0,cr1,sr0,sr1;
        { // i=1
          float f=fM(s,e0);
          float bb=fM(c,e0);
          slartgf(g,f,&c,&s,&r);
          g=fSb(d0,p);
          r=fA(fM(fSb(d1,g),s), fM(fM(2.0f,c),bb));
          p=fM(s,r);
          d0=fA(g,p);
          g=fSb(fM(c,r),bb);
          cr0=c; sr0=s;
        }
        { // i=2
          float f=fM(s,e1);
          float bb=fM(c,e1);
          slartgf(g,f,&c,&s,&r);
          e0=r;
          g=fSb(d1,p);
          r=fA(fM(fSb(d2,g),s), fM(fM(2.0f,c),bb));
          p=fM(s,r);
          d1=fA(g,p);
          g=fSb(fM(c,r),bb);
          cr1=c; sr1=s;
        }
        if (cr0!=1.0f || sr0!=0.0f) ZROT0(cr0, sr0);
        if (cr1!=1.0f || sr1!=0.0f) ZROT1(cr1, sr1);
        d2=fSb(d2,p);
        e1=g;
      }
    }
    if (iscale==1){
      float mv=fDv(anorm,SSFMAX);
      for (int i=lsv;i<=lendsv;++i) DSET(i-1, fM(DGET(i-1),mv));
      for (int i=lsv;i<=lendsv-1;++i) ESET(i-1, fM(EGET(i-1),mv));
    } else if (iscale==2){
      float mv=fDv(anorm,SSFMIN);
      for (int i=lsv;i<=lendsv;++i) DSET(i-1, fM(DGET(i-1),mv));
      for (int i=lsv;i<=lendsv-1;++i) ESET(i-1, fM(EGET(i-1),mv));
    }
    if (jtot>=nmaxit){ skip_sort=true; break; }
  }
  if (!skip_sort){
    for (int ii=2; ii<=3; ++ii){
      int i=ii-1, k=i; float p=DGET(i-1);
      for (int j=ii; j<=3; ++j) if (DGET(j-1)<p){ k=j; p=DGET(j-1); }
      if (k!=i){
        DSET(k-1, DGET(i-1)); DSET(i-1, p);
        ZSWAPC(i-1, k-1);
      }
    }
  }
  float o0=z0, o1=z1, o2=z2;
  if (tau1!=0.0f){
#if BLAS_FMA
    float wv=fF(hv2, o2, o1);
    float t2=fM(-tau1, wv);
    o1=fA(o1, t2);
    o2=fF(t2, hv2, o2);
#else
    float wv=fA(o1, fM(o2,hv2));
    float t2=fM(-tau1, wv);
    o1=fA(o1, t2);
    o2=fA(o2, fM(hv2,t2));
#endif
  }
  vout[0]=o0; vout[1]=o1; vout[2]=o2;
#undef DGET
#undef DSET
#undef EGET
#undef ESET
#undef ZGET
#undef ZSET
#undef ZROT0
#undef ZROT1
#undef ZSWAPC
}

struct KP {
  const float* x; const float* rs; const float* rl;
  const float *w1,*b1,*g1,*be1,*m1,*v1;
  const float *w2,*b2,*g2,*be2,*m2,*v2;
  const float *w3,*b3,*g3,*be3,*m3,*v3;
  const float *w4,*b4,*g4,*be4,*m4,*v4;
  float* out;
};

// R16 ws layout:
//  region A: per-point idx record, 128 u16 = 256 B (R8 format):
//    [0..63]=idxL, [64..95]=idxS, [96]=cl, [97]=cs
//  region S (offset BN*256): SoA xs[BN], ys[BN], zs[BN], sq[BN]
#define WS_STRIDE 128

// ---- Kernel 0: AoS->SoA transpose + sq precompute (same op chain as scan's sqj)
__global__ __launch_bounds__(256) void soa_kernel(const float* __restrict__ x,
                                                  float* __restrict__ xs, float* __restrict__ ys,
                                                  float* __restrict__ zs, float* __restrict__ sq,
                                                  int BN){
  int i=blockIdx.x*256+threadIdx.x;
  if (i<BN){
    float a=x[3*i], b=x[3*i+1], c=x[3*i+2];
    xs[i]=a; ys[i]=b; zs[i]=c;
    sq[i]=fA(fA(fM(a,a),fM(b,b)),fM(c,c));
  }
}

// ---- Kernel 1: wave-per-point ballot scan (R7-validated membership order),
// SoA coalesced loads (R9-validated), u16 INDEX records (R8 format).
__global__ __launch_bounds__(64) void scan_kernel(const float* __restrict__ rsp,
                                                  const float* __restrict__ rlp,
                                                  unsigned short* __restrict__ ws,
                                                  const float* __restrict__ xs,
                                                  const float* __restrict__ ys,
                                                  const float* __restrict__ zs,
                                                  const float* __restrict__ sq){
  const int lane=threadIdx.x;
  const int pt=blockIdx.x;
  const int b=pt>>12, n=pt&4095;
  const int g0=b<<12;
  const double rds=rint((double)rsp[0]*1e7)/1e7;
  const double rdl=rint((double)rlp[0]*1e7)/1e7;
  const float rr_s=(float)(rds*rds);
  const float rr_l=(float)(rdl*rdl);
  const float px=xs[g0+n], py=ys[g0+n], pz=zs[g0+n];
  const float sqn=sq[g0+n];
  unsigned short* w=ws+(size_t)pt*WS_STRIDE;
  int cs=0, cl=0;
  for (int c=0;c<64;++c){
    int j=c*64+lane;
    int gj=g0+j;
    float qx=xs[gj], qy=ys[gj], qz=zs[gj];
    float sqj=sq[gj];
    float dot=fA(fA(fM(px,qx),fM(py,qy)),fM(pz,qz));
    float d2=fSb(fA(sqn,sqj), fM(2.0f,dot));
    bool pl=!(d2>rr_l);
    bool ps=!(d2>rr_s);
    unsigned long long bl=__ballot(pl);
    unsigned long long bs=__ballot(ps);
    unsigned long long ltm=(1ull<<lane)-1ull;
    int posl=cl+__popcll(bl&ltm);
    int poss=cs+__popcll(bs&ltm);
    if (pl&&posl<64) w[posl]=(unsigned short)j;
    if (ps&&poss<32) w[64+poss]=(unsigned short)j;
    cl+=__popcll(bl); if(cl>64) cl=64;
    cs+=__popcll(bs); if(cs>32) cs=32;
    if (cs>=32&&cl>=64) break;          // wave-uniform
  }
  if (lane==0){ w[96]=(unsigned short)cl; w[97]=(unsigned short)cs; }
}

// ---- Kernel 2 (R16): fused moments+eig+MLP, 16 ACTIVE LANES PER WAVE.
// 32768 tasks / 64 lanes gave only 512 waves on 1024 SIMDs (half idle, no
// latency overlap for the serial eig chain — R7/R8 counters: Occ 5%, VALU 12%).
// Spreading over 2048 waves x 16 active lanes puts 2 waves/SIMD so chains
// interleave. Body is R8's validated momeig verbatim (AoS gather: x,y,z share
// one cache line); only the task->lane mapping changes.
__global__ __launch_bounds__(64) void momeig_kernel(KP kp,
                                                    const unsigned short* __restrict__ ws){
  const int lane=threadIdx.x;
  if (lane>=16) return;
  const int t=blockIdx.x*16+lane;       // task id < 2*BN
  const int p=t>>1, which=t&1;
  const int b=p>>12;
  const float* P=kp.x+(size_t)b*(4096*3);
  const unsigned char* recB=(const unsigned char*)(ws+(size_t)p*WS_STRIDE);
  const uint4* q=(const uint4*)(recB + (which? 0 : 128));
  uint4 v0=q[0], v1=q[1], v2=q[2], v3=q[3];
  uint4 v4=q[4], v5=q[5], v6=q[6], v7=q[7];
  const unsigned int cw=*(const unsigned int*)(recB+192); // lo16=cl, hi16=cs
  const int cnt = which? (int)(cw&0xFFFFu) : (int)(cw>>16);
  const int trip= which? 64 : 32;
  unsigned int a[32]={v0.x,v0.y,v0.z,v0.w, v1.x,v1.y,v1.z,v1.w,
                      v2.x,v2.y,v2.z,v2.w, v3.x,v3.y,v3.z,v3.w,
                      v4.x,v4.y,v4.z,v4.w, v5.x,v5.y,v5.z,v5.w,
                      v6.x,v6.y,v6.z,v6.w, v7.x,v7.y,v7.z,v7.w};
  const int j0=(int)(a[0]&0xFFFFu);

  float sx=0.0f, sy=0.0f, sz=0.0f;
#pragma unroll
  for (int k=0;k<64;++k){
    int raw=(k&1)? (int)(a[k>>1]>>16) : (int)(a[k>>1]&0xFFFFu);
    int idx=(k<cnt)? raw : j0;
    float cx=P[3*idx], cy=P[3*idx+1], cz=P[3*idx+2];
    float nx=fA(sx,cx), ny=fA(sy,cy), nz=fA(sz,cz);
    bool en=(k<trip);
    sx=en?nx:sx; sy=en?ny:sy; sz=en?nz:sz;
  }
  const float dv=which? 64.0f : 32.0f;
  const float mx=fDv(sx,dv), my=fDv(sy,dv), mz=fDv(sz,dv);

  float c0=0,c1=0,c2=0,c3=0,c4=0,c5=0;
#pragma unroll
  for (int k=0;k<64;++k){
    int raw=(k&1)? (int)(a[k>>1]>>16) : (int)(a[k>>1]&0xFFFFu);
    int idx=(k<cnt)? raw : j0;
    float cx=fSb(P[3*idx],mx), cy=fSb(P[3*idx+1],my), cz=fSb(P[3*idx+2],mz);
    float t0=fA(c0,fM(cx,cx)), t1=fA(c1,fM(cy,cx)), t2=fA(c2,fM(cz,cx));
    float t3=fA(c3,fM(cy,cy)), t4=fA(c4,fM(cz,cy)), t5=fA(c5,fM(cz,cz));
    bool en=(k<trip);
    c0=en?t0:c0; c1=en?t1:c1; c2=en?t2:c2;
    c3=en?t3:c3; c4=en?t4:c4; c5=en?t5:c5;
  }

  float v[3];
  eig3_smallest(c0,c1,c2,c3,c4,c5,v);

  // partner normal (lane^1): even lane has small, odd has large (both active)
  float pn0=__shfl_xor(v[0],1);
  float pn1=__shfl_xor(v[1],1);
  float pn2=__shfl_xor(v[2],1);

  if ((lane&1)==0){
    float dx=fM(fSb(v[0],pn0),0.5f);
    float dy=fM(fSb(v[1],pn1),0.5f);
    float dz=fM(fSb(v[2],pn2),0.5f);
    float curv=fQ(fA(fA(fM(dx,dx),fM(dy,dy)),fM(dz,dz)));

    float h1[16];
#pragma unroll
    for (int j=0;j<16;++j){
      float a0=fA(fM(kp.w1[j],curv), kp.b1[j]);
      a0=fA(fM(fDv(fSb(a0,kp.m1[j]), fQ(fA(kp.v1[j],1e-5f))), kp.g1[j]), kp.be1[j]);
      h1[j]=fmaxf(a0,0.0f);
    }
    float h2[32];
#pragma unroll
    for (int j=0;j<32;++j){
      float a0=0.0f;
#pragma unroll
      for (int k=0;k<16;++k) a0=fF(h1[k], kp.w2[j*16+k], a0);
      a0=fA(a0, kp.b2[j]);
      a0=fA(fM(fDv(fSb(a0,kp.m2[j]), fQ(fA(kp.v2[j],1e-5f))), kp.g2[j]), kp.be2[j]);
      h2[j]=fmaxf(a0,0.0f);
    }
    float h3[16];
#pragma unroll
    for (int j=0;j<16;++j){
      float a0=0.0f;
#pragma unroll
      for (int k=0;k<32;++k) a0=fF(h2[k], kp.w3[j*32+k], a0);
      a0=fA(a0, kp.b3[j]);
      a0=fA(fM(fDv(fSb(a0,kp.m3[j]), fQ(fA(kp.v3[j],1e-5f))), kp.g3[j]), kp.be3[j]);
      h3[j]=fmaxf(a0,0.0f);
    }
    float o=0.0f;
#pragma unroll
    for (int k=0;k<16;++k) o=fF(h3[k], kp.w4[k], o);
    o=fA(o, kp.b4[0]);
    o=fA(fM(fDv(fSb(o,kp.m4[0]), fQ(fA(kp.v4[0],1e-5f))), kp.g4[0]), kp.be4[0]);
    kp.out[p]=o;
  }
}

// ---- Fallback: monolithic kernel (used only if ws is too small) ----
__global__ __launch_bounds__(256) void freq_kernel(KP kp){
  __shared__ float sP[4096*3];
  __shared__ float sSq[4096];
  __shared__ unsigned short sIdxL[64][66];
  __shared__ unsigned short sIdxS[64][34];
  __shared__ unsigned char sCntL[64], sCntS[64];
  const int tid=threadIdx.x;
  const int lane=tid&63, wid=tid>>6;
  const int b=blockIdx.x>>6;
  const int n0=(blockIdx.x&63)*64;
  const float* P=kp.x+(size_t)b*(4096*3);
  for (int i=tid;i<4096*3;i+=256) sP[i]=P[i];
  for (int j=tid;j<4096;j+=256){
    float qx=P[3*j],qy=P[3*j+1],qz=P[3*j+2];
    sSq[j]=fA(fA(fM(qx,qx),fM(qy,qy)),fM(qz,qz));
  }
  __syncthreads();
  const double rds=rint((double)kp.rs[0]*1e7)/1e7;
  const double rdl=rint((double)kp.rl[0]*1e7)/1e7;
  const float rr_s=(float)(rds*rds);
  const float rr_l=(float)(rdl*rdl);
  for (int pi=0; pi<16; ++pi){
    const int pl_i=wid*16+pi;
    const int n=n0+pl_i;
    const float px=sP[3*n], py=sP[3*n+1], pz=sP[3*n+2];
    const float sqn=sSq[n];
    int cs=0, cl=0;
    for (int c=0;c<64;++c){
      int j=c*64+lane;
      float dot=fA(fA(fM(px,sP[3*j]),fM(py,sP[3*j+1])),fM(pz,sP[3*j+2]));
      float d2=fSb(fA(sqn,sSq[j]), fM(2.0f,dot));
      bool pl_=!(d2>rr_l);
      bool ps_=!(d2>rr_s);
      unsigned long long bl=__ballot(pl_);
      unsigned long long bs=__ballot(ps_);
      unsigned long long ltm=(1ull<<lane)-1ull;
      int posl=cl+__popcll(bl&ltm);
      int poss=cs+__popcll(bs&ltm);
      if (pl_&&posl<64) sIdxL[pl_i][posl]=(unsigned short)j;
      if (ps_&&poss<32) sIdxS[pl_i][poss]=(unsigned short)j;
      cl+=__popcll(bl); if(cl>64) cl=64;
      cs+=__popcll(bs); if(cs>32) cs=32;
      if (cs>=32&&cl>=64) break;
    }
    if (lane==0){ sCntL[pl_i]=(unsigned char)cl; sCntS[pl_i]=(unsigned char)cs; }
  }
  __syncthreads();
  if (lane<16){
    const int pl_i=wid*16+lane;
    const int ptg=blockIdx.x*64+pl_i;
    const int csn=sCntS[pl_i], cln=sCntL[pl_i];
    const int j0s=sIdxS[pl_i][0], j0l=sIdxL[pl_i][0];
    float ssx=0.0f,ssy=0.0f,ssz=0.0f, slx=0.0f,sly=0.0f,slz=0.0f;
    for (int k=0;k<32;++k){
      int idx=(k<csn)?(int)sIdxS[pl_i][k]:j0s;
      ssx=fA(ssx,sP[3*idx]); ssy=fA(ssy,sP[3*idx+1]); ssz=fA(ssz,sP[3*idx+2]);
    }
    for (int k=0;k<64;++k){
      int idx=(k<cln)?(int)sIdxL[pl_i][k]:j0l;
      slx=fA(slx,sP[3*idx]); sly=fA(sly,sP[3*idx+1]); slz=fA(slz,sP[3*idx+2]);
    }
    const float msx=fDv(ssx,32.0f), msy=fDv(ssy,32.0f), msz=fDv(ssz,32.0f);
    const float mlx=fDv(slx,64.0f), mly=fDv(sly,64.0f), mlz=fDv(slz,64.0f);
    float sc0=0,sc1=0,sc2=0,sc3=0,sc4=0,sc5=0;
    for (int k=0;k<32;++k){
      int idx=(k<csn)?(int)sIdxS[pl_i][k]:j0s;
      float cx=fSb(sP[3*idx],msx), cy=fSb(sP[3*idx+1],msy), cz=fSb(sP[3*idx+2],msz);
      sc0=fA(sc0,fM(cx,cx)); sc1=fA(sc1,fM(cy,cx)); sc2=fA(sc2,fM(cz,cx));
      sc3=fA(sc3,fM(cy,cy)); sc4=fA(sc4,fM(cz,cy)); sc5=fA(sc5,fM(cz,cz));
    }
    float lc0=0,lc1=0,lc2=0,lc3=0,lc4=0,lc5=0;
    for (int k=0;k<64;++k){
      int idx=(k<cln)?(int)sIdxL[pl_i][k]:j0l;
      float cx=fSb(sP[3*idx],mlx), cy=fSb(sP[3*idx+1],mly), cz=fSb(sP[3*idx+2],mlz);
      lc0=fA(lc0,fM(cx,cx)); lc1=fA(lc1,fM(cy,cx)); lc2=fA(lc2,fM(cz,cx));
      lc3=fA(lc3,fM(cy,cy)); lc4=fA(lc4,fM(cz,cy)); lc5=fA(lc5,fM(cz,cz));
    }
    float snv[3], lnv[3];
    eig3_smallest(sc0,sc1,sc2,sc3,sc4,sc5, snv);
    eig3_smallest(lc0,lc1,lc2,lc3,lc4,lc5, lnv);
    float dx=fM(fSb(snv[0],lnv[0]),0.5f);
    float dy=fM(fSb(snv[1],lnv[1]),0.5f);
    float dz=fM(fSb(snv[2],lnv[2]),0.5f);
    float curv=fQ(fA(fA(fM(dx,dx),fM(dy,dy)),fM(dz,dz)));
    float h1[16];
#pragma unroll
    for (int j=0;j<16;++j){
      float a0=fA(fM(kp.w1[j],curv), kp.b1[j]);
      a0=fA(fM(fDv(fSb(a0,kp.m1[j]), fQ(fA(kp.v1[j],1e-5f))), kp.g1[j]), kp.be1[j]);
      h1[j]=fmaxf(a0,0.0f);
    }
    float h2[32];
#pragma unroll
    for (int j=0;j<32;++j){
      float a0=0.0f;
#pragma unroll
      for (int k=0;k<16;++k) a0=fF(h1[k], kp.w2[j*16+k], a0);
      a0=fA(a0, kp.b2[j]);
      a0=fA(fM(fDv(fSb(a0,kp.m2[j]), fQ(fA(kp.v2[j],1e-5f))), kp.g2[j]), kp.be2[j]);
      h2[j]=fmaxf(a0,0.0f);
    }
    float h3[16];
#pragma unroll
    for (int j=0;j<16;++j){
      float a0=0.0f;
#pragma unroll
      for (int k=0;k<32;++k) a0=fF(h2[k], kp.w3[j*32+k], a0);
      a0=fA(a0, kp.b3[j]);
      a0=fA(fM(fDv(fSb(a0,kp.m3[j]), fQ(fA(kp.v3[j],1e-5f))), kp.g3[j]), kp.be3[j]);
      h3[j]=fmaxf(a0,0.0f);
    }
    float o=0.0f;
#pragma unroll
    for (int k=0;k<16;++k) o=fF(h3[k], kp.w4[k], o);
    o=fA(o, kp.b4[0]);
    o=fA(fM(fDv(fSb(o,kp.m4[0]), fQ(fA(kp.v4[0],1e-5f))), kp.g4[0]), kp.be4[0]);
    kp.out[ptg]=o;
  }
}

extern "C" void kernel_launch(void* const* d_in, const int* in_sizes, int n_in,
                              void* d_out, int out_size, void* d_ws, size_t ws_size,
                              hipStream_t stream){
  (void)n_in; (void)out_size;
  KP kp;
  kp.x  =(const float*)d_in[0];
  kp.rs =(const float*)d_in[1];
  kp.rl =(const float*)d_in[2];
  kp.w1 =(const float*)d_in[3];  kp.b1 =(const float*)d_in[4];  kp.g1 =(const float*)d_in[5];
  kp.be1=(const float*)d_in[6];  kp.m1 =(const float*)d_in[7];  kp.v1 =(const float*)d_in[8];
  kp.w2 =(const float*)d_in[9];  kp.b2 =(const float*)d_in[10]; kp.g2 =(const float*)d_in[11];
  kp.be2=(const float*)d_in[12]; kp.m2 =(const float*)d_in[13]; kp.v2 =(const float*)d_in[14];
  kp.w3 =(const float*)d_in[15]; kp.b3 =(const float*)d_in[16]; kp.g3 =(const float*)d_in[17];
  kp.be3=(const float*)d_in[18]; kp.m3 =(const float*)d_in[19]; kp.v3 =(const float*)d_in[20];
  kp.w4 =(const float*)d_in[21]; kp.b4 =(const float*)d_in[22]; kp.g4 =(const float*)d_in[23];
  kp.be4=(const float*)d_in[24]; kp.m4 =(const float*)d_in[25]; kp.v4 =(const float*)d_in[26];
  kp.out=(float*)d_out;
  const int BN=in_sizes[0]/3;               // B*N points
  // ws: region A (idx records, BN*256 B) + region S (SoA, BN*16 B)
  const size_t recBytes=(size_t)BN*256;
  const size_t ws_need=recBytes+(size_t)BN*16;
  if (ws_size>=ws_need){
    unsigned short* wsA=(unsigned short*)d_ws;
    float* xs=(float*)((char*)d_ws+recBytes);
    float* ys=xs+BN;
    float* zs=ys+BN;
    float* sqv=zs+BN;
    soa_kernel<<<(BN+255)/256, 256, 0, stream>>>(kp.x, xs, ys, zs, sqv, BN);
    scan_kernel<<<BN, 64, 0, stream>>>(kp.rs, kp.rl, wsA, xs, ys, zs, sqv);
    momeig_kernel<<<BN/8, 64, 0, stream>>>(kp, wsA);
  } else {
    freq_kernel<<<BN/64, 256, 0, stream>>>(kp);
  }
}

// Round 11
// 173.385 us; speedup vs baseline: 1.1150x; 1.1150x over previous
//
#include <hip/hip_runtime.h>
#include <math.h>

// ---- variant toggles (validated in R6) ----
#define BLAS_FMA 1
#define SYR2_VARIANT 0

#define DEV static __device__ __forceinline__

// f32 IEEE ops, opaque to fp-contract
DEV float fA(float a, float b){ return __fadd_rn(a,b); }
DEV float fSb(float a, float b){ return __fsub_rn(a,b); }
DEV float fM(float a, float b){ return __fmul_rn(a,b); }
DEV float fDv(float a, float b){ return __fdiv_rn(a,b); }
DEV float fQ(float a){ return __fsqrt_rn(a); }
DEV float fF(float a, float b, float c){ return __builtin_fmaf(a,b,c); }
DEV float fSGN(float a, float b){ return copysignf(a,b); }

DEV float slapy2f(float x, float y){
  float xa=fabsf(x), ya=fabsf(y);
  float w=fmaxf(xa,ya), z=fminf(xa,ya);
  if (z==0.0f) return w;
  float t=fDv(z,w);
  return fM(w, fQ(fA(1.0f, fM(t,t))));
}

// LAPACK >=3.10 slartg (f32)
DEV void slartgf(float f, float g, float* c, float* s, float* r){
  const float safmin=1.17549435e-38f;
  const float safmax=8.50705917e+37f;
  const float rtmin=1.08420217e-19f;
  const float rtmax=6.52169543e+18f;
  float f1=fabsf(f), g1=fabsf(g);
  if (g==0.0f){ *c=1.0f; *s=0.0f; *r=f; }
  else if (f==0.0f){ *c=0.0f; *s=fSGN(1.0f,g); *r=g1; }
  else {
    if (f1>rtmin && f1<rtmax && g1>rtmin && g1<rtmax){
      float d=fQ(fA(fM(f,f), fM(g,g)));
      *c=fDv(f1,d);
      *r=fSGN(d,f);
      *s=fDv(g,*r);
    } else {
      float u=fminf(safmax, fmaxf(safmin, fmaxf(f1,g1)));
      float fs=fDv(f,u), gs=fDv(g,u);
      float d=fQ(fA(fM(fs,fs), fM(gs,gs)));
      *c=fDv(fabsf(fs), d);
      *r=fSGN(d,f);
      *s=fDv(gs,*r);
      *r=fM(*r,u);
    }
  }
}

DEV void slaev2f(float a, float b, float c, float* rt1, float* rt2, float* cs1, float* sn1){
  float sm=fA(a,c);
  float df=fSb(a,c);
  float adf=fabsf(df);
  float tb=fA(b,b);
  float ab=fabsf(tb);
  float acmx, acmn;
  if (fabsf(a)>fabsf(c)){ acmx=a; acmn=c; } else { acmx=c; acmn=a; }
  float rt;
  if (adf>ab){ float t=fDv(ab,adf); rt=fM(adf, fQ(fA(1.0f, fM(t,t)))); }
  else if (adf<ab){ float t=fDv(adf,ab); rt=fM(ab, fQ(fA(1.0f, fM(t,t)))); }
  else { rt=fM(ab, fQ(2.0f)); }
  int sgn1;
  if (sm<0.0f){
    *rt1=fM(0.5f, fSb(sm,rt)); sgn1=-1;
    *rt2=fSb(fM(fDv(acmx,*rt1),acmn), fM(fDv(b,*rt1),b));
  } else if (sm>0.0f){
    *rt1=fM(0.5f, fA(sm,rt)); sgn1=1;
    *rt2=fSb(fM(fDv(acmx,*rt1),acmn), fM(fDv(b,*rt1),b));
  } else {
    *rt1=fM(0.5f,rt); *rt2=fM(-0.5f,rt); sgn1=1;
  }
  float cs; int sgn2;
  if (df>=0.0f){ cs=fA(df,rt); sgn2=1; } else { cs=fSb(df,rt); sgn2=-1; }
  float acs=fabsf(cs);
  if (acs>ab){
    float ct=fDv(-tb,cs);
    *sn1=fDv(1.0f, fQ(fA(1.0f, fM(ct,ct))));
    *cs1=fM(ct,*sn1);
  } else {
    if (ab==0.0f){ *cs1=1.0f; *sn1=0.0f; }
    else {
      float tn=fDv(-cs,tb);
      *cs1=fDv(1.0f, fQ(fA(1.0f, fM(tn,tn))));
      *sn1=fM(tn,*cs1);
    }
  }
  if (sgn1==sgn2){ float tn=*cs1; *cs1=-(*sn1); *sn1=tn; }
}

// f32 ssyevd(n=3,'L','V') emulating scipy-openblas32.
// R14: n=3 control-flow specialization (R8-validated, absmax 0.0009765625).
DEV void eig3_smallest(float a00, float a10, float a20, float a11, float a21, float a22,
                       float* vout){
  const float RMIN=3.13916472e-16f;
  const float RMAX=3.18559313e+15f;
  float anrm=fmaxf(fabsf(a00), fmaxf(fabsf(a10), fmaxf(fabsf(a20),
             fmaxf(fabsf(a11), fmaxf(fabsf(a21), fabsf(a22))))));
  if (anrm>0.0f && anrm<RMIN){
    float sig=fDv(RMIN,anrm);
    a00=fM(a00,sig); a10=fM(a10,sig); a20=fM(a20,sig);
    a11=fM(a11,sig); a21=fM(a21,sig); a22=fM(a22,sig);
  } else if (anrm>RMAX){
    float sig=fDv(RMAX,anrm);
    a00=fM(a00,sig); a10=fM(a10,sig); a20=fM(a20,sig);
    a11=fM(a11,sig); a21=fM(a21,sig); a22=fM(a22,sig);
  }
  float d0,d1,d2, e0,e1;
  float tau1=0.0f, hv2=0.0f;
  {
    float xnorm=fabsf(a20);
    if (xnorm==0.0f){
      tau1=0.0f;
      d0=a00; d1=a11; d2=a22;
      e0=a10; e1=a21;
    } else {
      float alpha=a10;
      float beta=-fSGN(slapy2f(alpha,xnorm), alpha);
      tau1=fDv(fSb(beta,alpha), beta);
      float rs=fDv(1.0f, fSb(alpha,beta));
      hv2=fM(a20, rs);
      float t2a=fM(a21, hv2);
#if BLAS_FMA
      float w1=fF(tau1, t2a, fM(tau1, a11));
      float w2=fF(fM(tau1,hv2), a22, fM(tau1, a21));
      float sd=fF(hv2, w2, w1);
#else
      float w1=fA(fM(tau1,a11), fM(tau1,t2a));
      float w2=fA(fM(tau1,a21), fM(fM(tau1,hv2),a22));
      float sd=fA(w1, fM(w2,hv2));
#endif
      float al2=fM(fM(-0.5f,tau1), sd);
      float nw1=fA(w1, al2);
#if BLAS_FMA
      float nw2=fF(al2, hv2, w2);
#else
      float nw2=fA(w2, fM(al2,hv2));
#endif
      w1=nw1; w2=nw2;
      float b11, b21, b22;
#if SYR2_VARIANT==0
      b11=fA(a11, fM(-2.0f, w1));
      b21=fA(a21, fF(hv2, -w1, -w2));
      b22=fA(a22, fF(hv2, -w2, fM(w2, -hv2)));
#elif SYR2_VARIANT==1
      b11=fSb(fSb(a11, w1), w1);
      b21=fSb(fF(hv2, -w1, a21), w2);
      b22=fF(w2, -hv2, fF(hv2, -w2, a22));
#else
      b11=fA(fA(a11, -w1), -w1);
      b21=fA(fA(a21, fM(hv2,-w1)), -w2);
      b22=fA(fA(a22, fM(hv2,-w2)), fM(w2,-hv2));
#endif
      d0=a00; d1=b11; d2=b22;
      e0=beta; e1=b21;
    }
  }
  // z column-major: z[r + 3*c] ; col0={z0,z1,z2} col1={z3,z4,z5} col2={z6,z7,z8}
  float z0=1.0f,z1=0.0f,z2=0.0f, z3=0.0f,z4=1.0f,z5=0.0f, z6=0.0f,z7=0.0f,z8=1.0f;

#define DGET(iA)   ((iA)==0?d0:((iA)==1?d1:d2))
#define DSET(iA,vA) do{ float _dsv=(vA); int _dsi=(iA); \
  d0=(_dsi==0)?_dsv:d0; d1=(_dsi==1)?_dsv:d1; d2=(_dsi==2)?_dsv:d2; }while(0)
#define EGET(iA)   ((iA)==0?e0:e1)
#define ESET(iA,vA) do{ float _esv=(vA); int _esi=(iA); \
  e0=(_esi==0)?_esv:e0; e1=(_esi==1)?_esv:e1; }while(0)
#define ZGET(rA,cA) ((cA)==0? ((rA)==0?z0:((rA)==1?z1:z2)) : ((cA)==1? ((rA)==0?z3:((rA)==1?z4:z5)) : ((rA)==0?z6:((rA)==1?z7:z8))))
#define ZSET(rA,cA,vA) do{ float _zsv=(vA); int _zsr=(rA), _zsc=(cA); \
  z0=(_zsr==0&&_zsc==0)?_zsv:z0; z1=(_zsr==1&&_zsc==0)?_zsv:z1; z2=(_zsr==2&&_zsc==0)?_zsv:z2; \
  z3=(_zsr==0&&_zsc==1)?_zsv:z3; z4=(_zsr==1&&_zsc==1)?_zsv:z4; z5=(_zsr==2&&_zsc==1)?_zsv:z5; \
  z6=(_zsr==0&&_zsc==2)?_zsv:z6; z7=(_zsr==1&&_zsc==2)?_zsv:z7; z8=(_zsr==2&&_zsc==2)?_zsv:z8; }while(0)
// constant-column plane rotations
#define ZROT0(ccA,ssA) do{ float _zc=(ccA), _zs=(ssA); \
  float _t0=z3, _a0=z0; z3=fSb(fM(_zc,_t0),fM(_zs,_a0)); z0=fA(fM(_zs,_t0),fM(_zc,_a0)); \
  float _t1=z4, _a1=z1; z4=fSb(fM(_zc,_t1),fM(_zs,_a1)); z1=fA(fM(_zs,_t1),fM(_zc,_a1)); \
  float _t2=z5, _a2=z2; z5=fSb(fM(_zc,_t2),fM(_zs,_a2)); z2=fA(fM(_zs,_t2),fM(_zc,_a2)); }while(0)
#define ZROT1(ccA,ssA) do{ float _zc=(ccA), _zs=(ssA); \
  float _t0=z6, _a0=z3; z6=fSb(fM(_zc,_t0),fM(_zs,_a0)); z3=fA(fM(_zs,_t0),fM(_zc,_a0)); \
  float _t1=z7, _a1=z4; z7=fSb(fM(_zc,_t1),fM(_zs,_a1)); z4=fA(fM(_zs,_t1),fM(_zc,_a1)); \
  float _t2=z8, _a2=z5; z8=fSb(fM(_zc,_t2),fM(_zs,_a2)); z5=fA(fM(_zs,_t2),fM(_zc,_a2)); }while(0)
#define ZSWAPC(caA,cbA) do{ int _zwa=(caA), _zwb=(cbA); \
  _Pragma("unroll") \
  for (int _zwr=0;_zwr<3;++_zwr){ \
    float _zwta=ZGET(_zwr,_zwa); float _zwtb=ZGET(_zwr,_zwb); \
    ZSET(_zwr,_zwa,_zwtb); ZSET(_zwr,_zwb,_zwta); \
  } }while(0)

  const float EPS=5.96046448e-08f;
  const float EPS2=3.55271368e-15f;
  const float SAFMIN=1.17549435e-38f;
  const float SSFMAX=3.07445735e+18f;
  const float SSFMIN=3.05175781e-05f;
  int l1=1, jtot=0; const int nmaxit=90;
  bool skip_sort=false;
  while (l1<=3){
    if (l1>1) ESET(l1-2, 0.0f);
    int m=3;
    for (int mm=l1; mm<=2; ++mm){
      float tst=fabsf(EGET(mm-1));
      if (tst==0.0f){ m=mm; break; }
      if (tst<=fM(fM(fQ(fabsf(DGET(mm-1))), fQ(fabsf(DGET(mm)))), EPS)){ ESET(mm-1,0.0f); m=mm; break; }
    }
    int l=l1, lsv=l, lend=m, lendsv=m;
    l1=m+1;
    if (lend==l) continue;
    float anorm=fabsf(DGET(lend-1));
    for (int i=l; i<=lend-1; ++i){ anorm=fmaxf(anorm,fabsf(DGET(i-1))); anorm=fmaxf(anorm,fabsf(EGET(i-1))); }
    if (anorm==0.0f) continue;
    int iscale=0;
    if (anorm>SSFMAX){
      iscale=1; float mv=fDv(SSFMAX,anorm);
      for (int i=l;i<=lend;++i) DSET(i-1, fM(DGET(i-1),mv));
      for (int i=l;i<=lend-1;++i) ESET(i-1, fM(EGET(i-1),mv));
    } else if (anorm<SSFMIN){
      iscale=2; float mv=fDv(SSFMIN,anorm);
      for (int i=l;i<=lend;++i) DSET(i-1, fM(DGET(i-1),mv));
      for (int i=l;i<=lend-1;++i) ESET(i-1, fM(EGET(i-1),mv));
    }
    if (fabsf(DGET(lend-1))<fabsf(DGET(l-1))){ lend=lsv; l=lendsv; }
    if (lend>l){
      for (;;){
        int M=lend;
        if (l!=lend){
          for (int mm=l; mm<=lend-1; ++mm){
            float ee=fabsf(EGET(mm-1));
            float tst=fM(ee,ee);
            if (tst<=fA(fM(fM(EPS2,fabsf(DGET(mm-1))), fabsf(DGET(mm))), SAFMIN)){ M=mm; break; }
          }
        }
        if (M<lend) ESET(M-1,0.0f);
        float p=DGET(l-1);
        if (M==l){
          l+=1;
          if (l<=lend) continue; else break;
        }
        if (M==l+1){
          float rt1,rt2,cc,ss;
          if (l==1){
            slaev2f(d0, e0, d1, &rt1,&rt2,&cc,&ss);
            ZROT0(cc, ss);
            d0=rt1; d1=rt2; e0=0.0f;
          } else { // l==2
            slaev2f(d1, e1, d2, &rt1,&rt2,&cc,&ss);
            ZROT1(cc, ss);
            d1=rt1; d2=rt2; e1=0.0f;
          }
          l+=2;
          if (l<=lend) continue; else break;
        }
        if (jtot==nmaxit) break;
        ++jtot;
        float g=fDv(fSb(d1,p), fM(2.0f,e0));
        float r=slapy2f(g,1.0f);
        g=fA(fSb(d2,p), fDv(e0, fA(g, fSGN(r,g))));
        float s=1.0f, c=1.0f; p=0.0f;
        float cr0,cr1,sr0,sr1;
        { // i=2
          float f=fM(s,e1);
          float bb=fM(c,e1);
          slartgf(g,f,&c,&s,&r);
          g=fSb(d2,p);
          r=fA(fM(fSb(d1,g),s), fM(fM(2.0f,c),bb));
          p=fM(s,r);
          d2=fA(g,p);
          g=fSb(fM(c,r),bb);
          cr1=c; sr1=-s;
        }
        { // i=1
          float f=fM(s,e0);
          float bb=fM(c,e0);
          slartgf(g,f,&c,&s,&r);
          e1=r;
          g=fSb(d1,p);
          r=fA(fM(fSb(d0,g),s), fM(fM(2.0f,c),bb));
          p=fM(s,r);
          d1=fA(g,p);
          g=fSb(fM(c,r),bb);
          cr0=c; sr0=-s;
        }
        if (cr1!=1.0f || sr1!=0.0f) ZROT1(cr1, sr1);
        if (cr0!=1.0f || sr0!=0.0f) ZROT0(cr0, sr0);
        d0=fSb(d0,p);
        e0=g;
      }
    } else {
      for (;;){
        int M=lend;
        if (l!=lend){
          for (int mm=l; mm>=lend+1; --mm){
            float ee=fabsf(EGET(mm-2));
            float tst=fM(ee,ee);
            if (tst<=fA(fM(fM(EPS2,fabsf(DGET(mm-1))), fabsf(DGET(mm-2))), SAFMIN)){ M=mm; break; }
          }
        }
        if (M>lend) ESET(M-2,0.0f);
        float p=DGET(l-1);
        if (M==l){
          l-=1;
          if (l>=lend) continue; else break;
        }
        if (M==l-1){
          float rt1,rt2,cc,ss;
          if (l==3){
            slaev2f(d1, e1, d2, &rt1,&rt2,&cc,&ss);
            ZROT1(cc, ss);
            d1=rt1; d2=rt2; e1=0.0f;
          } else { // l==2
            slaev2f(d0, e0, d1, &rt1,&rt2,&cc,&ss);
            ZROT0(cc, ss);
            d0=rt1; d1=rt2; e0=0.0f;
          }
          l-=2;
          if (l>=lend) continue; else break;
        }
        if (jtot==nmaxit) break;
        ++jtot;
        float g=fDv(fSb(d1,p), fM(2.0f,e1));
        float r=slapy2f(g,1.0f);
        g=fA(fSb(d0,p), fDv(e1, fA(g, fSGN(r,g))));
        float s=1.0f, c=1.0f; p=0.0f;
        float cr0,cr1,sr0,sr1;
        { // i=1
          float f=fM(s,e0);
          float bb=fM(c,e0);
          slartgf(g,f,&c,&s,&r);
          g=fSb(d0,p);
          r=fA(fM(fSb(d1,g),s), fM(fM(2.0f,c),bb));
          p=fM(s,r);
          d0=fA(g,p);
          g=fSb(fM(c,r),bb);
          cr0=c; sr0=s;
        }
        { // i=2
          float f=fM(s,e1);
          float bb=fM(c,e1);
          slartgf(g,f,&c,&s,&r);
          e0=r;
          g=fSb(d1,p);
          r=fA(fM(fSb(d2,g),s), fM(fM(2.0f,c),bb));
          p=fM(s,r);
          d1=fA(g,p);
          g=fSb(fM(c,r),bb);
          cr1=c; sr1=s;
        }
        if (cr0!=1.0f || sr0!=0.0f) ZROT0(cr0, sr0);
        if (cr1!=1.0f || sr1!=0.0f) ZROT1(cr1, sr1);
        d2=fSb(d2,p);
        e1=g;
      }
    }
    if (iscale==1){
      float mv=fDv(anorm,SSFMAX);
      for (int i=lsv;i<=lendsv;++i) DSET(i-1, fM(DGET(i-1),mv));
      for (int i=lsv;i<=lendsv-1;++i) ESET(i-1, fM(EGET(i-1),mv));
    } else if (iscale==2){
      float mv=fDv(anorm,SSFMIN);
      for (int i=lsv;i<=lendsv;++i) DSET(i-1, fM(DGET(i-1),mv));
      for (int i=lsv;i<=lendsv-1;++i) ESET(i-1, fM(EGET(i-1),mv));
    }
    if (jtot>=nmaxit){ skip_sort=true; break; }
  }
  if (!skip_sort){
    for (int ii=2; ii<=3; ++ii){
      int i=ii-1, k=i; float p=DGET(i-1);
      for (int j=ii; j<=3; ++j) if (DGET(j-1)<p){ k=j; p=DGET(j-1); }
      if (k!=i){
        DSET(k-1, DGET(i-1)); DSET(i-1, p);
        ZSWAPC(i-1, k-1);
      }
    }
  }
  float o0=z0, o1=z1, o2=z2;
  if (tau1!=0.0f){
#if BLAS_FMA
    float wv=fF(hv2, o2, o1);
    float t2=fM(-tau1, wv);
    o1=fA(o1, t2);
    o2=fF(t2, hv2, o2);
#else
    float wv=fA(o1, fM(o2,hv2));
    float t2=fM(-tau1, wv);
    o1=fA(o1, t2);
    o2=fA(o2, fM(hv2,t2));
#endif
  }
  vout[0]=o0; vout[1]=o1; vout[2]=o2;
#undef DGET
#undef DSET
#undef EGET
#undef ESET
#undef ZGET
#undef ZSET
#undef ZROT0
#undef ZROT1
#undef ZSWAPC
}

struct KP {
  const float* x; const float* rs; const float* rl;
  const float *w1,*b1,*g1,*be1,*m1,*v1;
  const float *w2,*b2,*g2,*be2,*m2,*v2;
  const float *w3,*b3,*g3,*be3,*m3,*v3;
  const float *w4,*b4,*g4,*be4,*m4,*v4;
  float* out;
};

// R17 ws layout:
//  region A: per-point idx record, 128 u16 = 256 B (R8 format):
//    [0..63]=idxL, [64..95]=idxS, [96]=cl, [97]=cs
//  region B (offset BN*256): covB, BN*12 f32
//  region S (offset BN*304): SoA xs[BN], ys[BN], zs[BN], sq[BN]
#define WS_STRIDE 128

// ---- Kernel 0: AoS->SoA transpose + sq precompute (same op chain as scan's sqj)
__global__ __launch_bounds__(256) void soa_kernel(const float* __restrict__ x,
                                                  float* __restrict__ xs, float* __restrict__ ys,
                                                  float* __restrict__ zs, float* __restrict__ sq,
                                                  int BN){
  int i=blockIdx.x*256+threadIdx.x;
  if (i<BN){
    float a=x[3*i], b=x[3*i+1], c=x[3*i+2];
    xs[i]=a; ys[i]=b; zs[i]=c;
    sq[i]=fA(fA(fM(a,a),fM(b,b)),fM(c,c));
  }
}

// ---- Kernel 1: wave-per-point ballot scan (R7-validated membership order),
// SoA coalesced loads (R9/R10-validated), u16 INDEX records (R8 format).
__global__ __launch_bounds__(64) void scan_kernel(const float* __restrict__ rsp,
                                                  const float* __restrict__ rlp,
                                                  unsigned short* __restrict__ ws,
                                                  const float* __restrict__ xs,
                                                  const float* __restrict__ ys,
                                                  const float* __restrict__ zs,
                                                  const float* __restrict__ sq){
  const int lane=threadIdx.x;
  const int pt=blockIdx.x;
  const int b=pt>>12, n=pt&4095;
  const int g0=b<<12;
  const double rds=rint((double)rsp[0]*1e7)/1e7;
  const double rdl=rint((double)rlp[0]*1e7)/1e7;
  const float rr_s=(float)(rds*rds);
  const float rr_l=(float)(rdl*rdl);
  const float px=xs[g0+n], py=ys[g0+n], pz=zs[g0+n];
  const float sqn=sq[g0+n];
  unsigned short* w=ws+(size_t)pt*WS_STRIDE;
  int cs=0, cl=0;
  for (int c=0;c<64;++c){
    int j=c*64+lane;
    int gj=g0+j;
    float qx=xs[gj], qy=ys[gj], qz=zs[gj];
    float sqj=sq[gj];
    float dot=fA(fA(fM(px,qx),fM(py,qy)),fM(pz,qz));
    float d2=fSb(fA(sqn,sqj), fM(2.0f,dot));
    bool pl=!(d2>rr_l);
    bool ps=!(d2>rr_s);
    unsigned long long bl=__ballot(pl);
    unsigned long long bs=__ballot(ps);
    unsigned long long ltm=(1ull<<lane)-1ull;
    int posl=cl+__popcll(bl&ltm);
    int poss=cs+__popcll(bs&ltm);
    if (pl&&posl<64) w[posl]=(unsigned short)j;
    if (ps&&poss<32) w[64+poss]=(unsigned short)j;
    cl+=__popcll(bl); if(cl>64) cl=64;
    cs+=__popcll(bs); if(cs>32) cs=32;
    if (cs>=32&&cl>=64) break;          // wave-uniform
  }
  if (lane==0){ w[96]=(unsigned short)cl; w[97]=(unsigned short)cs; }
}

// ---- Kernel 2 (R2-validated): task-per-lane moments, no LDS, record in VGPRs.
__global__ __launch_bounds__(64) void moments2_kernel(const float* __restrict__ x,
                                                      const unsigned short* __restrict__ ws,
                                                      float* __restrict__ covB){
  const int lane=threadIdx.x;
  const int t=blockIdx.x*64+lane;       // task id < 2*BN
  const int p=t>>1, which=t&1;          // adjacent lanes share a point's record
  const int b=p>>12;
  const float* P=x+(size_t)b*(4096*3);
  const unsigned char* recB=(const unsigned char*)(ws+(size_t)p*WS_STRIDE);
  const uint4* q=(const uint4*)(recB + (which? 0 : 128));
  uint4 v0=q[0], v1=q[1], v2=q[2], v3=q[3];
  uint4 v4=q[4], v5=q[5], v6=q[6], v7=q[7];
  const unsigned int cw=*(const unsigned int*)(recB+192); // lo16=cl, hi16=cs
  const int cnt = which? (int)(cw&0xFFFFu) : (int)(cw>>16);
  const int trip= which? 64 : 32;
  unsigned int a[32]={v0.x,v0.y,v0.z,v0.w, v1.x,v1.y,v1.z,v1.w,
                      v2.x,v2.y,v2.z,v2.w, v3.x,v3.y,v3.z,v3.w,
                      v4.x,v4.y,v4.z,v4.w, v5.x,v5.y,v5.z,v5.w,
                      v6.x,v6.y,v6.z,v6.w, v7.x,v7.y,v7.z,v7.w};
  const int j0=(int)(a[0]&0xFFFFu);

  float sx=0.0f, sy=0.0f, sz=0.0f;
#pragma unroll
  for (int k=0;k<64;++k){
    int raw=(k&1)? (int)(a[k>>1]>>16) : (int)(a[k>>1]&0xFFFFu);
    int idx=(k<cnt)? raw : j0;
    float cx=P[3*idx], cy=P[3*idx+1], cz=P[3*idx+2];
    float nx=fA(sx,cx), ny=fA(sy,cy), nz=fA(sz,cz);
    bool en=(k<trip);
    sx=en?nx:sx; sy=en?ny:sy; sz=en?nz:sz;
  }
  const float dv=which? 64.0f : 32.0f;
  const float mx=fDv(sx,dv), my=fDv(sy,dv), mz=fDv(sz,dv);

  float c0=0,c1=0,c2=0,c3=0,c4=0,c5=0;
#pragma unroll
  for (int k=0;k<64;++k){
    int raw=(k&1)? (int)(a[k>>1]>>16) : (int)(a[k>>1]&0xFFFFu);
    int idx=(k<cnt)? raw : j0;
    float cx=fSb(P[3*idx],mx), cy=fSb(P[3*idx+1],my), cz=fSb(P[3*idx+2],mz);
    float t0=fA(c0,fM(cx,cx)), t1=fA(c1,fM(cy,cx)), t2=fA(c2,fM(cz,cx));
    float t3=fA(c3,fM(cy,cy)), t4=fA(c4,fM(cz,cy)), t5=fA(c5,fM(cz,cz));
    bool en=(k<trip);
    c0=en?t0:c0; c1=en?t1:c1; c2=en?t2:c2;
    c3=en?t3:c3; c4=en?t4:c4; c5=en?t5:c5;
  }

  float* cb=covB+(size_t)p*12+which*6;
  cb[0]=c0; cb[1]=c1; cb[2]=c2; cb[3]=c3; cb[4]=c4; cb[5]=c5;
}

// ---- Kernel 3 (R6 structure + R14 eig3): eig (2-lane redundancy, 32 eigs/wave,
// 1024 waves = 1/SIMD machine-wide) + fused curvature/MLP ----
__global__ __launch_bounds__(64) void eigmlp_kernel(KP kp, const float* __restrict__ covB){
  __shared__ float sN[32][3];
  const int lane=threadIdx.x;
  const int g=lane>>1;                    // group 0..31
  const int t=blockIdx.x*32+g;            // task id < 2*BN
  const int p=t>>1, which=t&1;            // which: 0=small, 1=large
  const float* cb=covB+(size_t)p*12+which*6;
  float v[3];
  eig3_smallest(cb[0],cb[1],cb[2],cb[3],cb[4],cb[5],v);
  if ((lane&1)==0){ sN[g][0]=v[0]; sN[g][1]=v[1]; sN[g][2]=v[2]; }
  __syncthreads();

  if (lane<16){
    const int pt=blockIdx.x*16+lane;
    const float* sn=sN[2*lane];           // which=0 (small)
    const float* ln=sN[2*lane+1];         // which=1 (large)
    float dx=fM(fSb(sn[0],ln[0]),0.5f);
    float dy=fM(fSb(sn[1],ln[1]),0.5f);
    float dz=fM(fSb(sn[2],ln[2]),0.5f);
    float curv=fQ(fA(fA(fM(dx,dx),fM(dy,dy)),fM(dz,dz)));

    float h1[16];
#pragma unroll
    for (int j=0;j<16;++j){
      float a0=fA(fM(kp.w1[j],curv), kp.b1[j]);
      a0=fA(fM(fDv(fSb(a0,kp.m1[j]), fQ(fA(kp.v1[j],1e-5f))), kp.g1[j]), kp.be1[j]);
      h1[j]=fmaxf(a0,0.0f);
    }
    float h2[32];
#pragma unroll
    for (int j=0;j<32;++j){
      float a0=0.0f;
#pragma unroll
      for (int k=0;k<16;++k) a0=fF(h1[k], kp.w2[j*16+k], a0);
      a0=fA(a0, kp.b2[j]);
      a0=fA(fM(fDv(fSb(a0,kp.m2[j]), fQ(fA(kp.v2[j],1e-5f))), kp.g2[j]), kp.be2[j]);
      h2[j]=fmaxf(a0,0.0f);
    }
    float h3[16];
#pragma unroll
    for (int j=0;j<16;++j){
      float a0=0.0f;
#pragma unroll
      for (int k=0;k<32;++k) a0=fF(h2[k], kp.w3[j*32+k], a0);
      a0=fA(a0, kp.b3[j]);
      a0=fA(fM(fDv(fSb(a0,kp.m3[j]), fQ(fA(kp.v3[j],1e-5f))), kp.g3[j]), kp.be3[j]);
      h3[j]=fmaxf(a0,0.0f);
    }
    float o=0.0f;
#pragma unroll
    for (int k=0;k<16;++k) o=fF(h3[k], kp.w4[k], o);
    o=fA(o, kp.b4[0]);
    o=fA(fM(fDv(fSb(o,kp.m4[0]), fQ(fA(kp.v4[0],1e-5f))), kp.g4[0]), kp.be4[0]);
    kp.out[pt]=o;
  }
}

// ---- Fallback: monolithic kernel (used only if ws is too small) ----
__global__ __launch_bounds__(256) void freq_kernel(KP kp){
  __shared__ float sP[4096*3];
  __shared__ float sSq[4096];
  __shared__ unsigned short sIdxL[64][66];
  __shared__ unsigned short sIdxS[64][34];
  __shared__ unsigned char sCntL[64], sCntS[64];
  const int tid=threadIdx.x;
  const int lane=tid&63, wid=tid>>6;
  const int b=blockIdx.x>>6;
  const int n0=(blockIdx.x&63)*64;
  const float* P=kp.x+(size_t)b*(4096*3);
  for (int i=tid;i<4096*3;i+=256) sP[i]=P[i];
  for (int j=tid;j<4096;j+=256){
    float qx=P[3*j],qy=P[3*j+1],qz=P[3*j+2];
    sSq[j]=fA(fA(fM(qx,qx),fM(qy,qy)),fM(qz,qz));
  }
  __syncthreads();
  const double rds=rint((double)kp.rs[0]*1e7)/1e7;
  const double rdl=rint((double)kp.rl[0]*1e7)/1e7;
  const float rr_s=(float)(rds*rds);
  const float rr_l=(float)(rdl*rdl);
  for (int pi=0; pi<16; ++pi){
    const int pl_i=wid*16+pi;
    const int n=n0+pl_i;
    const float px=sP[3*n], py=sP[3*n+1], pz=sP[3*n+2];
    const float sqn=sSq[n];
    int cs=0, cl=0;
    for (int c=0;c<64;++c){
      int j=c*64+lane;
      float dot=fA(fA(fM(px,sP[3*j]),fM(py,sP[3*j+1])),fM(pz,sP[3*j+2]));
      float d2=fSb(fA(sqn,sSq[j]), fM(2.0f,dot));
      bool pl_=!(d2>rr_l);
      bool ps_=!(d2>rr_s);
      unsigned long long bl=__ballot(pl_);
      unsigned long long bs=__ballot(ps_);
      unsigned long long ltm=(1ull<<lane)-1ull;
      int posl=cl+__popcll(bl&ltm);
      int poss=cs+__popcll(bs&ltm);
      if (pl_&&posl<64) sIdxL[pl_i][posl]=(unsigned short)j;
      if (ps_&&poss<32) sIdxS[pl_i][poss]=(unsigned short)j;
      cl+=__popcll(bl); if(cl>64) cl=64;
      cs+=__popcll(bs); if(cs>32) cs=32;
      if (cs>=32&&cl>=64) break;
    }
    if (lane==0){ sCntL[pl_i]=(unsigned char)cl; sCntS[pl_i]=(unsigned char)cs; }
  }
  __syncthreads();
  if (lane<16){
    const int pl_i=wid*16+lane;
    const int ptg=blockIdx.x*64+pl_i;
    const int csn=sCntS[pl_i], cln=sCntL[pl_i];
    const int j0s=sIdxS[pl_i][0], j0l=sIdxL[pl_i][0];
    float ssx=0.0f,ssy=0.0f,ssz=0.0f, slx=0.0f,sly=0.0f,slz=0.0f;
    for (int k=0;k<32;++k){
      int idx=(k<csn)?(int)sIdxS[pl_i][k]:j0s;
      ssx=fA(ssx,sP[3*idx]); ssy=fA(ssy,sP[3*idx+1]); ssz=fA(ssz,sP[3*idx+2]);
    }
    for (int k=0;k<64;++k){
      int idx=(k<cln)?(int)sIdxL[pl_i][k]:j0l;
      slx=fA(slx,sP[3*idx]); sly=fA(sly,sP[3*idx+1]); slz=fA(slz,sP[3*idx+2]);
    }
    const float msx=fDv(ssx,32.0f), msy=fDv(ssy,32.0f), msz=fDv(ssz,32.0f);
    const float mlx=fDv(slx,64.0f), mly=fDv(sly,64.0f), mlz=fDv(slz,64.0f);
    float sc0=0,sc1=0,sc2=0,sc3=0,sc4=0,sc5=0;
    for (int k=0;k<32;++k){
      int idx=(k<csn)?(int)sIdxS[pl_i][k]:j0s;
      float cx=fSb(sP[3*idx],msx), cy=fSb(sP[3*idx+1],msy), cz=fSb(sP[3*idx+2],msz);
      sc0=fA(sc0,fM(cx,cx)); sc1=fA(sc1,fM(cy,cx)); sc2=fA(sc2,fM(cz,cx));
      sc3=fA(sc3,fM(cy,cy)); sc4=fA(sc4,fM(cz,cy)); sc5=fA(sc5,fM(cz,cz));
    }
    float lc0=0,lc1=0,lc2=0,lc3=0,lc4=0,lc5=0;
    for (int k=0;k<64;++k){
      int idx=(k<cln)?(int)sIdxL[pl_i][k]:j0l;
      float cx=fSb(sP[3*idx],mlx), cy=fSb(sP[3*idx+1],mly), cz=fSb(sP[3*idx+2],mlz);
      lc0=fA(lc0,fM(cx,cx)); lc1=fA(lc1,fM(cy,cx)); lc2=fA(lc2,fM(cz,cx));
      lc3=fA(lc3,fM(cy,cy)); lc4=fA(lc4,fM(cz,cy)); lc5=fA(lc5,fM(cz,cz));
    }
    float snv[3], lnv[3];
    eig3_smallest(sc0,sc1,sc2,sc3,sc4,sc5, snv);
    eig3_smallest(lc0,lc1,lc2,lc3,lc4,lc5, lnv);
    float dx=fM(fSb(snv[0],lnv[0]),0.5f);
    float dy=fM(fSb(snv[1],lnv[1]),0.5f);
    float dz=fM(fSb(snv[2],lnv[2]),0.5f);
    float curv=fQ(fA(fA(fM(dx,dx),fM(dy,dy)),fM(dz,dz)));
    float h1[16];
#pragma unroll
    for (int j=0;j<16;++j){
      float a0=fA(fM(kp.w1[j],curv), kp.b1[j]);
      a0=fA(fM(fDv(fSb(a0,kp.m1[j]), fQ(fA(kp.v1[j],1e-5f))), kp.g1[j]), kp.be1[j]);
      h1[j]=fmaxf(a0,0.0f);
    }
    float h2[32];
#pragma unroll
    for (int j=0;j<32;++j){
      float a0=0.0f;
#pragma unroll
      for (int k=0;k<16;++k) a0=fF(h1[k], kp.w2[j*16+k], a0);
      a0=fA(a0, kp.b2[j]);
      a0=fA(fM(fDv(fSb(a0,kp.m2[j]), fQ(fA(kp.v2[j],1e-5f))), kp.g2[j]), kp.be2[j]);
      h2[j]=fmaxf(a0,0.0f);
    }
    float h3[16];
#pragma unroll
    for (int j=0;j<16;++j){
      float a0=0.0f;
#pragma unroll
      for (int k=0;k<32;++k) a0=fF(h2[k], kp.w3[j*32+k], a0);
      a0=fA(a0, kp.b3[j]);
      a0=fA(fM(fDv(fSb(a0,kp.m3[j]), fQ(fA(kp.v3[j],1e-5f))), kp.g3[j]), kp.be3[j]);
      h3[j]=fmaxf(a0,0.0f);
    }
    float o=0.0f;
#pragma unroll
    for (int k=0;k<16;++k) o=fF(h3[k], kp.w4[k], o);
    o=fA(o, kp.b4[0]);
    o=fA(fM(fDv(fSb(o,kp.m4[0]), fQ(fA(kp.v4[0],1e-5f))), kp.g4[0]), kp.be4[0]);
    kp.out[ptg]=o;
  }
}

extern "C" void kernel_launch(void* const* d_in, const int* in_sizes, int n_in,
                              void* d_out, int out_size, void* d_ws, size_t ws_size,
                              hipStream_t stream){
  (void)n_in; (void)out_size;
  KP kp;
  kp.x  =(const float*)d_in[0];
  kp.rs =(const float*)d_in[1];
  kp.rl =(const float*)d_in[2];
  kp.w1 =(const float*)d_in[3];  kp.b1 =(const float*)d_in[4];  kp.g1 =(const float*)d_in[5];
  kp.be1=(const float*)d_in[6];  kp.m1 =(const float*)d_in[7];  kp.v1 =(const float*)d_in[8];
  kp.w2 =(const float*)d_in[9];  kp.b2 =(const float*)d_in[10]; kp.g2 =(const float*)d_in[11];
  kp.be2=(const float*)d_in[12]; kp.m2 =(const float*)d_in[13]; kp.v2 =(const float*)d_in[14];
  kp.w3 =(const float*)d_in[15]; kp.b3 =(const float*)d_in[16]; kp.g3 =(const float*)d_in[17];
  kp.be3=(const float*)d_in[18]; kp.m3 =(const float*)d_in[19]; kp.v3 =(const float*)d_in[20];
  kp.w4 =(const float*)d_in[21]; kp.b4 =(const float*)d_in[22]; kp.g4 =(const float*)d_in[23];
  kp.be4=(const float*)d_in[24]; kp.m4 =(const float*)d_in[25]; kp.v4 =(const float*)d_in[26];
  kp.out=(float*)d_out;
  const int BN=in_sizes[0]/3;               // B*N points
  // ws: region A (idx records, BN*256 B) + region B (cov, BN*48 B) + region S (SoA, BN*16 B)
  const size_t recBytes=(size_t)BN*256;
  const size_t covBytes=(size_t)BN*48;
  const size_t ws_need=recBytes+covBytes+(size_t)BN*16;
  if (ws_size>=ws_need){
    unsigned short* wsA=(unsigned short*)d_ws;
    float* covB=(float*)((char*)d_ws+recBytes);
    float* xs=(float*)((char*)d_ws+recBytes+covBytes);
    float* ys=xs+BN;
    float* zs=ys+BN;
    float* sqv=zs+BN;
    soa_kernel<<<(BN+255)/256, 256, 0, stream>>>(kp.x, xs, ys, zs, sqv, BN);
    scan_kernel<<<BN, 64, 0, stream>>>(kp.rs, kp.rl, wsA, xs, ys, zs, sqv);
    moments2_kernel<<<BN/32, 64, 0, stream>>>(kp.x, wsA, covB);
    eigmlp_kernel<<<BN/16, 64, 0, stream>>>(kp, covB);
  } else {
    freq_kernel<<<BN/64, 256, 0, stream>>>(kp);
  }
}